// Round 1
// baseline (128.524 us; speedup 1.0000x reference)
//
#include <hip/hip_runtime.h>
#include <hip/hip_bf16.h>

// Problem constants (from reference setup_inputs)
#define BDIM 256     // batch
#define NDIM 1152    // route nodes
#define CIN 8
#define KDIM 10      // num capsule groups
#define COUT 16
#define NTHREADS 256
#define PADC 17      // LDS row stride for pred (16 cols + 1 pad)

__global__ __launch_bounds__(NTHREADS)
void capsule_routing_kernel(const float* __restrict__ x,      // [B, N, CIN]
                            const float* __restrict__ w,      // [K, N, CIN, COUT]
                            const int*   __restrict__ niter_p,
                            float*       __restrict__ out)    // [K, B, COUT]
{
    __shared__ float pred[NDIM * PADC];   // 1152*17*4 = 78336 B

    const int blk = blockIdx.x;           // k * BDIM + b  (k outer => L2 reuse of W[k])
    const int k = blk >> 8;               // BDIM == 256
    const int b = blk & (BDIM - 1);
    const int t = threadIdx.x;

    const float* __restrict__ xb = x + (size_t)b * NDIM * CIN;
    const float* __restrict__ wk = w + (size_t)k * NDIM * CIN * COUT;

    // -------- Phase 1: pred[n][co] = sum_i x[b,n,i] * W[k,n,i,co] --------
    // idx fast in co => W loads are 16 contiguous floats per n (coalesced).
    for (int idx = t; idx < NDIM * COUT; idx += NTHREADS) {
        const int n  = idx >> 4;
        const int co = idx & 15;
        const float* xr = xb + n * CIN;
        const float* wr = wk + n * CIN * COUT + co;
        float acc = 0.f;
#pragma unroll
        for (int i = 0; i < CIN; ++i)
            acc = fmaf(xr[i], wr[i * COUT], acc);
        pred[n * PADC + co] = acc;
    }
    __syncthreads();

    // -------- Phase 2: per-co statistics (sum, max, min) --------
    // 16 lanes per co; lanes sharing a co are contiguous within a wave.
    const int co = t >> 4;
    const int l  = t & 15;

    float psum = 0.f, pmax = -3.4e38f, pmin = 3.4e38f;
    for (int n = l; n < NDIM; n += 16) {
        const float p = pred[n * PADC + co];
        psum += p;
        pmax = fmaxf(pmax, p);
        pmin = fminf(pmin, p);
    }
#pragma unroll
    for (int m = 1; m < 16; m <<= 1) {
        psum += __shfl_xor(psum, m, 64);
        pmax = fmaxf(pmax, __shfl_xor(pmax, m, 64));
        pmin = fminf(pmin, __shfl_xor(pmin, m, 64));
    }

    const int niter = *niter_p;

    // Iteration 1: logits == 0 -> softmax uniform -> s = mean_n(pred)
    float s  = psum * (1.0f / (float)NDIM);
    float v  = s * fabsf(s) / (1.f + s * s);   // squash (singleton dim): s*|s|/(1+s^2)
    float vc = v;                              // cumulative v => logits = pred * vc

    for (int it = 1; it < niter; ++it) {
        // max over n of pred*vc: sign-aware, no extra LDS pass
        const float m = (vc >= 0.f) ? vc * pmax : vc * pmin;
        float se = 0.f, sp = 0.f;
        for (int n = l; n < NDIM; n += 16) {
            const float p = pred[n * PADC + co];
            const float e = __expf(p * vc - m);
            se += e;
            sp += e * p;
        }
#pragma unroll
        for (int mm = 1; mm < 16; mm <<= 1) {
            se += __shfl_xor(se, mm, 64);
            sp += __shfl_xor(sp, mm, 64);
        }
        s  = sp / se;
        v  = s * fabsf(s) / (1.f + s * s);
        vc += v;
    }

    if (l == 0)
        out[(size_t)blk * COUT + co] = v;
}

extern "C" void kernel_launch(void* const* d_in, const int* in_sizes, int n_in,
                              void* d_out, int out_size, void* d_ws, size_t ws_size,
                              hipStream_t stream) {
    const float* x = (const float*)d_in[0];
    const float* w = (const float*)d_in[1];
    const int* niter = (const int*)d_in[2];
    float* out = (float*)d_out;

    const int grid = KDIM * BDIM;   // 2560 blocks, k outer
    capsule_routing_kernel<<<grid, NTHREADS, 0, stream>>>(x, w, niter, out);
}